// Round 1
// baseline (434.102 us; speedup 1.0000x reference)
//
#include <hip/hip_runtime.h>
#include <math.h>

#define HID 4096

// ---------------------------------------------------------------------------
// Phase 1: six matvecs y_g = W_g @ x + b_g with fused activations.
// One 64-lane wave per output row; 6*4096 = 24576 row-tasks.
// gate: 0=q 1=k 2=v 3=i 4=f 5=o
// ---------------------------------------------------------------------------
__global__ __launch_bounds__(256) void matvec6_kernel(
    const float* __restrict__ x,
    const float* __restrict__ W0, const float* __restrict__ b0,
    const float* __restrict__ W1, const float* __restrict__ b1,
    const float* __restrict__ W2, const float* __restrict__ b2,
    const float* __restrict__ W3, const float* __restrict__ b3,
    const float* __restrict__ W4, const float* __restrict__ b4,
    const float* __restrict__ W5, const float* __restrict__ b5,
    float* __restrict__ ws)
{
    const int wave = (blockIdx.x * blockDim.x + threadIdx.x) >> 6;
    const int lane = threadIdx.x & 63;
    if (wave >= 6 * HID) return;
    const int gate = wave >> 12;   // / 4096
    const int row  = wave & (HID - 1);

    const float* W; const float* b;
    switch (gate) {
        case 0:  W = W0; b = b0; break;
        case 1:  W = W1; b = b1; break;
        case 2:  W = W2; b = b2; break;
        case 3:  W = W3; b = b3; break;
        case 4:  W = W4; b = b4; break;
        default: W = W5; b = b5; break;
    }

    const float4* Wr = (const float4*)(W + (size_t)row * HID);
    const float4* xv = (const float4*)x;

    float acc = 0.f;
    #pragma unroll
    for (int it = 0; it < HID / 4 / 64; ++it) {   // 16 iterations
        const int idx = it * 64 + lane;
        float4 w  = Wr[idx];
        float4 xx = xv[idx];
        acc += w.x * xx.x + w.y * xx.y + w.z * xx.z + w.w * xx.w;
    }

    // wave-64 shuffle reduce
    #pragma unroll
    for (int off = 32; off > 0; off >>= 1)
        acc += __shfl_down(acc, off, 64);

    if (lane == 0) {
        float z = acc + b[row];
        float r;
        if (gate == 1)      r = z * (1.0f / 64.0f);            // k * 1/sqrt(H)
        else if (gate == 3) r = expf(z);                        // i = exp
        else if (gate >= 4) r = 1.0f / (1.0f + expf(-z));       // f, o sigmoid
        else                r = z;                              // q, v
        ws[gate * HID + row] = r;
    }
}

// ---------------------------------------------------------------------------
// Phase 2: n_t, B = i*k, FQ = f*q, scalars s_ikq = sum(i*k*q),
//          denom = max(|dot(n_t, q)|, 1).  Single block.
// ws layout (floats): [0)q [1)k [2)v [3)i [4)f [5)o [6)B [7)FQ [8*HID) scalars
// ---------------------------------------------------------------------------
__global__ __launch_bounds__(1024) void prep_kernel(
    const float* __restrict__ n_prev,
    float* __restrict__ ws,
    float* __restrict__ out_nt)
{
    const float* q  = ws;
    const float* k  = ws + 1 * HID;
    const float* iv = ws + 3 * HID;
    const float* f  = ws + 4 * HID;
    float* B    = ws + 6 * HID;
    float* FQ   = ws + 7 * HID;
    float* scal = ws + 8 * HID;

    __shared__ float s1[16], s2[16];

    float ikq = 0.f, nq = 0.f;
    for (int c = threadIdx.x; c < HID; c += blockDim.x) {
        float bc = iv[c] * k[c];
        float nt = f[c] * n_prev[c] + bc;
        B[c]  = bc;
        FQ[c] = f[c] * q[c];
        out_nt[c] = nt;
        ikq += bc * q[c];
        nq  += nt * q[c];
    }

    #pragma unroll
    for (int off = 32; off > 0; off >>= 1) {
        ikq += __shfl_down(ikq, off, 64);
        nq  += __shfl_down(nq,  off, 64);
    }
    const int wid  = threadIdx.x >> 6;
    const int lane = threadIdx.x & 63;
    if (lane == 0) { s1[wid] = ikq; s2[wid] = nq; }
    __syncthreads();
    if (threadIdx.x == 0) {
        float a = 0.f, nsum = 0.f;
        const int nw = blockDim.x >> 6;
        for (int w = 0; w < nw; ++w) { a += s1[w]; nsum += s2[w]; }
        scal[0] = a;                                  // s_ikq
        scal[1] = fmaxf(fabsf(nsum), 1.0f);           // denom
    }
}

// ---------------------------------------------------------------------------
// Phase 3: one block per row r:
//   c_t[r][c] = f[c]*c_prev[r][c] + v[r]*B[c]        (written out)
//   cq[r]     = sum_c FQ[c]*c_prev[r][c] + v[r]*s_ikq
//   h_t[r]    = o[r] * cq[r] / denom
// ---------------------------------------------------------------------------
__global__ __launch_bounds__(256) void finale_kernel(
    const float* __restrict__ c_prev,
    const float* __restrict__ ws,
    float* __restrict__ out_h,
    float* __restrict__ out_c)
{
    const int row = blockIdx.x;
    const float* v  = ws + 2 * HID;
    const float* o  = ws + 5 * HID;
    const float* f  = ws + 4 * HID;
    const float* B  = ws + 6 * HID;
    const float* FQ = ws + 7 * HID;
    const float s_ikq = ws[8 * HID + 0];
    const float denom = ws[8 * HID + 1];
    const float vr = v[row];

    const float4* cp  = (const float4*)(c_prev + (size_t)row * HID);
    float4*       ct  = (float4*)(out_c + (size_t)row * HID);
    const float4* f4  = (const float4*)f;
    const float4* B4  = (const float4*)B;
    const float4* FQ4 = (const float4*)FQ;

    float acc = 0.f;
    #pragma unroll
    for (int it = 0; it < (HID / 4) / 256; ++it) {    // 4 iterations
        const int idx = it * 256 + threadIdx.x;
        float4 c  = cp[idx];
        float4 ff = f4[idx];
        float4 bb = B4[idx];
        float4 fq = FQ4[idx];
        float4 r;
        r.x = ff.x * c.x + vr * bb.x;
        r.y = ff.y * c.y + vr * bb.y;
        r.z = ff.z * c.z + vr * bb.z;
        r.w = ff.w * c.w + vr * bb.w;
        ct[idx] = r;
        acc += fq.x * c.x + fq.y * c.y + fq.z * c.z + fq.w * c.w;
    }

    // block reduce acc (4 waves)
    #pragma unroll
    for (int off = 32; off > 0; off >>= 1)
        acc += __shfl_down(acc, off, 64);
    __shared__ float sred[4];
    const int wid  = threadIdx.x >> 6;
    const int lane = threadIdx.x & 63;
    if (lane == 0) sred[wid] = acc;
    __syncthreads();
    if (threadIdx.x == 0) {
        float cq = sred[0] + sred[1] + sred[2] + sred[3] + vr * s_ikq;
        out_h[row] = o[row] * cq / denom;
    }
}

// ---------------------------------------------------------------------------
extern "C" void kernel_launch(void* const* d_in, const int* in_sizes, int n_in,
                              void* d_out, int out_size, void* d_ws, size_t ws_size,
                              hipStream_t stream) {
    const float* x      = (const float*)d_in[0];
    // d_in[1] = h_prev (unused by the reference)
    const float* c_prev = (const float*)d_in[2];
    const float* n_prev = (const float*)d_in[3];
    const float* Wq_w = (const float*)d_in[4];  const float* Wq_b = (const float*)d_in[5];
    const float* Wk_w = (const float*)d_in[6];  const float* Wk_b = (const float*)d_in[7];
    const float* Wv_w = (const float*)d_in[8];  const float* Wv_b = (const float*)d_in[9];
    const float* Wi_w = (const float*)d_in[10]; const float* Wi_b = (const float*)d_in[11];
    const float* Wf_w = (const float*)d_in[12]; const float* Wf_b = (const float*)d_in[13];
    const float* Wo_w = (const float*)d_in[14]; const float* Wo_b = (const float*)d_in[15];

    float* out   = (float*)d_out;
    float* out_h = out;                                   // [HID]
    float* out_c = out + HID;                             // [HID*HID]
    float* out_n = out + HID + (size_t)HID * HID;         // [HID]

    float* ws = (float*)d_ws;   // needs (8*HID + 2) floats ~= 128 KB

    // Phase 1: 6*4096 waves, 4 waves/block
    {
        const int waves = 6 * HID;
        const int blocks = waves / 4;   // 6144
        matvec6_kernel<<<blocks, 256, 0, stream>>>(
            x, Wq_w, Wq_b, Wk_w, Wk_b, Wv_w, Wv_b,
            Wi_w, Wi_b, Wf_w, Wf_b, Wo_w, Wo_b, ws);
    }
    // Phase 2: scalars + n_t
    prep_kernel<<<1, 1024, 0, stream>>>(n_prev, ws, out_n);
    // Phase 3: c_t + h_t
    finale_kernel<<<HID, 256, 0, stream>>>(c_prev, ws, out_h, out_c);
}